// Round 1
// baseline (456.585 us; speedup 1.0000x reference)
//
#include <hip/hip_runtime.h>
#include <hip/hip_fp16.h>
#include <hip/hip_bf16.h>

#define NN 50000
#define EE 800000

// ---- workspace layout (fits proven-safe 12.8MB + flag envelope) ----
#define OFF_AGGH   0ull          // 50000*64*2  = 6,400,000 B  (f16 agg)
#define OFF_EID    6400000ull    // 800000*4    = 3,200,000 B  (edge id per CSR slot)
#define OFF_SRC    9600000ull    // 800000*2    = 1,600,000 B  (src as ushort, NN<65536)
#define OFF_ROWPTR 11200000ull   // 50001*4     =   200,004 B
#define OFF_CURSOR 11400008ull   // 50000*4     =   200,000 B  (counts, then cursor)
#define OFF_FLAG   12800000ull   // proven-safe offset from prior session

__device__ __forceinline__ float bflo(unsigned u) { return __uint_as_float(u << 16); }
__device__ __forceinline__ float bfhi(unsigned u) { return __uint_as_float(u & 0xffff0000u); }

// flag=1 if float tensors are bf16, 0 if f32 (proven R3/R6).
__global__ void detect_dtype(const unsigned* __restrict__ xw, int* __restrict__ flag) {
    const int t = threadIdx.x;  // 64 threads
    unsigned e = (xw[t] >> 7) & 0xFFu;
    unsigned long long m = __ballot(e >= 100u && e <= 140u);
    if (t == 0) *flag = (__popcll(m) >= 32) ? 1 : 0;
}

template <bool BF16>
__device__ __forceinline__ float edge_lin(const void* __restrict__ eav, int e,
                                          const float* __restrict__ we, float bed) {
    float acc = bed;
    if constexpr (BF16) {
        const uint4* row = (const uint4*)((const __hip_bfloat16*)eav + (size_t)e * 16);
        const uint4 p0 = row[0];
        const uint4 p1 = row[1];
        acc = fmaf(bflo(p0.x), we[0],  acc); acc = fmaf(bfhi(p0.x), we[1],  acc);
        acc = fmaf(bflo(p0.y), we[2],  acc); acc = fmaf(bfhi(p0.y), we[3],  acc);
        acc = fmaf(bflo(p0.z), we[4],  acc); acc = fmaf(bfhi(p0.z), we[5],  acc);
        acc = fmaf(bflo(p0.w), we[6],  acc); acc = fmaf(bfhi(p0.w), we[7],  acc);
        acc = fmaf(bflo(p1.x), we[8],  acc); acc = fmaf(bfhi(p1.x), we[9],  acc);
        acc = fmaf(bflo(p1.y), we[10], acc); acc = fmaf(bfhi(p1.y), we[11], acc);
        acc = fmaf(bflo(p1.z), we[12], acc); acc = fmaf(bfhi(p1.z), we[13], acc);
        acc = fmaf(bflo(p1.w), we[14], acc); acc = fmaf(bfhi(p1.w), we[15], acc);
    } else {
        const float4* row = (const float4*)((const float*)eav + (size_t)e * 16);
        const float4 q0 = row[0], q1 = row[1], q2 = row[2], q3 = row[3];
        acc = fmaf(q0.x, we[0],  acc); acc = fmaf(q0.y, we[1],  acc);
        acc = fmaf(q0.z, we[2],  acc); acc = fmaf(q0.w, we[3],  acc);
        acc = fmaf(q1.x, we[4],  acc); acc = fmaf(q1.y, we[5],  acc);
        acc = fmaf(q1.z, we[6],  acc); acc = fmaf(q1.w, we[7],  acc);
        acc = fmaf(q2.x, we[8],  acc); acc = fmaf(q2.y, we[9],  acc);
        acc = fmaf(q2.z, we[10], acc); acc = fmaf(q2.w, we[11], acc);
        acc = fmaf(q3.x, we[12], acc); acc = fmaf(q3.y, we[13], acc);
        acc = fmaf(q3.z, we[14], acc); acc = fmaf(q3.w, we[15], acc);
    }
    return acc;
}

// ---------------- CSR build: histogram of dst ----------------
__global__ __launch_bounds__(256) void hist_kernel(const int* __restrict__ ei,
                                                   int* __restrict__ cnt) {
    const int oddor = ei[1] | ei[3] | ei[5] | ei[7] | ei[9] | ei[11] | ei[13] | ei[15];
    const bool idx64 = (oddor == 0);
    const long long* __restrict__ ei64 = (const long long*)ei;
    const int gid = blockIdx.x * 256 + threadIdx.x;
    const int gs  = gridDim.x * 256;
    for (int e = gid; e < EE; e += gs) {
        const int dst = idx64 ? (int)ei64[EE + e] : ei[EE + e];
        atomicAdd(&cnt[dst], 1);
    }
}

// ---------------- CSR build: single-block exclusive scan ----------------
// cnt[] in: per-node counts; out: exclusive prefix (cursor init).
// rowptr[] out: exclusive prefix with rowptr[NN] = EE.
__global__ __launch_bounds__(1024) void scan_kernel(int* __restrict__ cnt,
                                                    int* __restrict__ rowptr) {
    __shared__ int part[1024];
    const int t  = threadIdx.x;
    const int CH = 49;                   // 1024*49 = 50176 >= 50000
    int lo = t * CH, hi = lo + CH;
    if (hi > NN) hi = NN;
    if (lo > NN) lo = NN;
    int s = 0;
    for (int i = lo; i < hi; i++) s += cnt[i];
    part[t] = s;
    __syncthreads();
    for (int off = 1; off < 1024; off <<= 1) {
        int add = (t >= off) ? part[t - off] : 0;
        __syncthreads();
        part[t] += add;
        __syncthreads();
    }
    int run = part[t] - s;               // exclusive base of this chunk
    for (int i = lo; i < hi; i++) {
        const int c = cnt[i];
        rowptr[i] = run;
        cnt[i]    = run;                 // cursor init
        run += c;
    }
    if (t == 1023) rowptr[NN] = part[1023];
}

// ---------------- CSR build: scatter (eid, src) records ----------------
__global__ __launch_bounds__(256) void scatter_kernel(const int* __restrict__ ei,
                                                      int* __restrict__ cursor,
                                                      int* __restrict__ recs_eid,
                                                      unsigned short* __restrict__ recs_src) {
    const int oddor = ei[1] | ei[3] | ei[5] | ei[7] | ei[9] | ei[11] | ei[13] | ei[15];
    const bool idx64 = (oddor == 0);
    const long long* __restrict__ ei64 = (const long long*)ei;
    const int gid = blockIdx.x * 256 + threadIdx.x;
    const int gs  = gridDim.x * 256;
    for (int e = gid; e < EE; e += gs) {
        int src, dst;
        if (idx64) { src = (int)ei64[e]; dst = (int)ei64[EE + e]; }
        else       { src = ei[e];        dst = ei[EE + e]; }
        const int p = atomicAdd(&cursor[dst], 1);
        recs_eid[p] = e;
        recs_src[p] = (unsigned short)src;
    }
}

// ---------------- gather aggregation: one wave per node, no atomics ----------------
template <bool BF16>
__device__ __forceinline__ void gather_body(
    const void* __restrict__ xv,
    const int* __restrict__ recs_eid, const unsigned short* __restrict__ recs_src,
    const int* __restrict__ rowptr,
    const void* __restrict__ eav, const void* __restrict__ Wev,
    const void* __restrict__ bev, __half* __restrict__ aggh)
{
    const int tid = threadIdx.x;
    const int d   = tid & 63;
    const int sub = tid >> 6;

    float we[16];
    float bed;
    if constexpr (BF16) {
        const __hip_bfloat16* We = (const __hip_bfloat16*)Wev;
#pragma unroll
        for (int k = 0; k < 16; k++) we[k] = __bfloat162float(We[k * 64 + d]);
        bed = __bfloat162float(((const __hip_bfloat16*)bev)[d]);
    } else {
        const float* We = (const float*)Wev;
#pragma unroll
        for (int k = 0; k < 16; k++) we[k] = We[k * 64 + d];
        bed = ((const float*)bev)[d];
    }

    const int wid = blockIdx.x * 4 + sub;
    const int nw  = gridDim.x * 4;
    for (int n = wid; n < NN; n += nw) {
        const int beg = rowptr[n];
        const int end = rowptr[n + 1];
        float agg = 0.0f;
        int k = beg;
        for (; k + 4 <= end; k += 4) {
            int e[4], s[4];
#pragma unroll
            for (int i = 0; i < 4; i++) { e[i] = recs_eid[k + i]; s[i] = (int)recs_src[k + i]; }
            float xs[4];
#pragma unroll
            for (int i = 0; i < 4; i++) {
                if constexpr (BF16)
                    xs[i] = __bfloat162float(((const __hip_bfloat16*)xv)[(size_t)s[i] * 64 + d]);
                else
                    xs[i] = ((const float*)xv)[(size_t)s[i] * 64 + d];
            }
            float acc[4];
#pragma unroll
            for (int i = 0; i < 4; i++) acc[i] = edge_lin<BF16>(eav, e[i], we, bed);
#pragma unroll
            for (int i = 0; i < 4; i++) agg += fmaxf(acc[i] + xs[i], 0.0f);
        }
        for (; k < end; ++k) {
            const int e0 = recs_eid[k];
            const int s0 = (int)recs_src[k];
            float x0;
            if constexpr (BF16)
                x0 = __bfloat162float(((const __hip_bfloat16*)xv)[(size_t)s0 * 64 + d]);
            else
                x0 = ((const float*)xv)[(size_t)s0 * 64 + d];
            agg += fmaxf(edge_lin<BF16>(eav, e0, we, bed) + x0, 0.0f);
        }
        aggh[(size_t)n * 64 + d] = __float2half(agg);
    }
}

__global__ __launch_bounds__(256) void gather_agg_kernel(
    const void* x, const int* recs_eid, const unsigned short* recs_src,
    const int* rowptr, const void* ea, const void* We, const void* be,
    __half* aggh, const int* flag)
{
    if (*flag) gather_body<true >(x, recs_eid, recs_src, rowptr, ea, We, be, aggh);
    else       gather_body<false>(x, recs_eid, recs_src, rowptr, ea, We, be, aggh);
}

// ---------------- MLP (unchanged from measured-best version) ----------------
template <bool BF16>
__device__ __forceinline__ void mlp_body(
    const void* __restrict__ xv, const __half* __restrict__ aggh,
    const void* __restrict__ W1v, const void* __restrict__ b1v,
    const void* __restrict__ W2v, const void* __restrict__ b2v,
    void* __restrict__ outv, float (*sh)[64], float (*st)[64])
{
    const int tid = threadIdx.x;
    const int d   = tid & 63;
    const int w   = tid >> 6;

    float w1c[64], w2c[64], b1d, b2d;
    if constexpr (BF16) {
        const __hip_bfloat16* W1 = (const __hip_bfloat16*)W1v;
        const __hip_bfloat16* W2 = (const __hip_bfloat16*)W2v;
#pragma unroll
        for (int k = 0; k < 64; k++) {
            w1c[k] = __bfloat162float(W1[k * 64 + d]);
            w2c[k] = __bfloat162float(W2[k * 64 + d]);
        }
        b1d = __bfloat162float(((const __hip_bfloat16*)b1v)[d]);
        b2d = __bfloat162float(((const __hip_bfloat16*)b2v)[d]);
    } else {
        const float* W1 = (const float*)W1v;
        const float* W2 = (const float*)W2v;
#pragma unroll
        for (int k = 0; k < 64; k++) {
            w1c[k] = W1[k * 64 + d];
            w2c[k] = W2[k * 64 + d];
        }
        b1d = ((const float*)b1v)[d];
        b2d = ((const float*)b2v)[d];
    }

    const int stride = gridDim.x * 4;
    int node = blockIdx.x * 4 + w;

    float xs_n = 0.0f, ag_n = 0.0f;
    if (node < NN) {
        if constexpr (BF16) xs_n = __bfloat162float(((const __hip_bfloat16*)xv)[(size_t)node * 64 + d]);
        else                xs_n = ((const float*)xv)[(size_t)node * 64 + d];
        ag_n = __half2float(aggh[(size_t)node * 64 + d]);
    }

    while (node < NN) {
        const float xs_c = xs_n, ag_c = ag_n;
        const int next = node + stride;
        if (next < NN) {
            if constexpr (BF16) xs_n = __bfloat162float(((const __hip_bfloat16*)xv)[(size_t)next * 64 + d]);
            else                xs_n = ((const float*)xv)[(size_t)next * 64 + d];
            ag_n = __half2float(aggh[(size_t)next * 64 + d]);
        }

        sh[w][d] = xs_c + ag_c;

        float t = b1d;
        const float4* hv = (const float4*)sh[w];
#pragma unroll
        for (int k = 0; k < 16; k++) {
            const float4 hq = hv[k];
            t = fmaf(hq.x, w1c[4 * k],     t);
            t = fmaf(hq.y, w1c[4 * k + 1], t);
            t = fmaf(hq.z, w1c[4 * k + 2], t);
            t = fmaf(hq.w, w1c[4 * k + 3], t);
        }
        t = fmaxf(t, 0.0f);
        st[w][d] = t;

        float o = b2d;
        const float4* tv = (const float4*)st[w];
#pragma unroll
        for (int k = 0; k < 16; k++) {
            const float4 tq = tv[k];
            o = fmaf(tq.x, w2c[4 * k],     o);
            o = fmaf(tq.y, w2c[4 * k + 1], o);
            o = fmaf(tq.z, w2c[4 * k + 2], o);
            o = fmaf(tq.w, w2c[4 * k + 3], o);
        }
        if constexpr (BF16) ((__hip_bfloat16*)outv)[(size_t)node * 64 + d] = __float2bfloat16(o);
        else                ((float*)outv)[(size_t)node * 64 + d] = o;
        node = next;
    }
}

__global__ __launch_bounds__(256) void mlp_kernel(
    const void* x, const __half* aggh,
    const void* W1, const void* b1, const void* W2, const void* b2,
    void* out, const int* flag)
{
    __shared__ float sh[4][64];
    __shared__ float st[4][64];
    if (*flag) mlp_body<true >(x, aggh, W1, b1, W2, b2, out, sh, st);
    else       mlp_body<false>(x, aggh, W1, b1, W2, b2, out, sh, st);
}

extern "C" void kernel_launch(void* const* d_in, const int* in_sizes, int n_in,
                              void* d_out, int out_size, void* d_ws, size_t ws_size,
                              hipStream_t stream) {
    const void* x          = d_in[0];
    const int*  edge_index = (const int*)d_in[1];
    const void* edge_attr  = d_in[2];
    const void* We         = d_in[3];
    const void* be         = d_in[4];
    const void* W1         = d_in[5];
    const void* b1         = d_in[6];
    const void* W2         = d_in[7];
    const void* b2         = d_in[8];

    char* ws = (char*)d_ws;
    __half*         aggh   = (__half*)(ws + OFF_AGGH);
    int*            eid    = (int*)(ws + OFF_EID);
    unsigned short* rsrc   = (unsigned short*)(ws + OFF_SRC);
    int*            rowptr = (int*)(ws + OFF_ROWPTR);
    int*            cursor = (int*)(ws + OFF_CURSOR);
    int*            flag   = (int*)(ws + OFF_FLAG);

    hipMemsetAsync(cursor, 0, (size_t)NN * sizeof(int), stream);
    hipLaunchKernelGGL(detect_dtype, dim3(1), dim3(64), 0, stream,
                       (const unsigned*)x, flag);
    hipLaunchKernelGGL(hist_kernel, dim3(1024), dim3(256), 0, stream,
                       edge_index, cursor);
    hipLaunchKernelGGL(scan_kernel, dim3(1), dim3(1024), 0, stream,
                       cursor, rowptr);
    hipLaunchKernelGGL(scatter_kernel, dim3(1024), dim3(256), 0, stream,
                       edge_index, cursor, eid, rsrc);
    hipLaunchKernelGGL(gather_agg_kernel, dim3(2048), dim3(256), 0, stream,
                       x, eid, rsrc, rowptr, edge_attr, We, be, aggh, flag);
    hipLaunchKernelGGL(mlp_kernel, dim3(768), dim3(256), 0, stream,
                       x, aggh, W1, b1, W2, b2, d_out, flag);
}

// Round 3
// 401.692 us; speedup vs baseline: 1.1367x; 1.1367x over previous
//
#include <hip/hip_runtime.h>
#include <hip/hip_fp16.h>
#include <hip/hip_bf16.h>

#define NN 50000
#define EE 800000
#define CAP 950000            // EE + 3*NN : padded-CSR capacity (each segment padded to x4)
#define SCAN_BLKS 196         // ceil(NN/256)

// ---- workspace layout (stays inside proven-safe 12.8MB + flag envelope) ----
#define OFF_AGGH   0ull          // 50000*64*2 = 6,400,000
#define OFF_EID    6400000ull    // 950000*4  = 3,800,000  -> ends 10,200,000
#define OFF_SRC    10200000ull   // 950000*2  = 1,900,000  -> ends 12,100,000
#define OFF_ROWPTR 12100000ull   // 50001*4   =   200,004  -> ends 12,300,004
#define OFF_CURSOR 12300008ull   // 50000*4   =   200,000  -> ends 12,500,008
#define OFF_PART   12500008ull   // 196*4     =       784  -> ends 12,500,792
#define OFF_PART2  12500800ull   // 196*4     =       784  -> ends 12,501,584
#define OFF_FLAG   12800000ull   // proven-safe offset from prior session

typedef int            iv4  __attribute__((ext_vector_type(4)));
typedef unsigned       uv4  __attribute__((ext_vector_type(4)));
typedef float          fv4  __attribute__((ext_vector_type(4)));
typedef unsigned short usv4 __attribute__((ext_vector_type(4)));

__device__ __forceinline__ float bflo(unsigned u) { return __uint_as_float(u << 16); }
__device__ __forceinline__ float bfhi(unsigned u) { return __uint_as_float(u & 0xffff0000u); }

// flag=1 if float tensors are bf16, 0 if f32 (proven R3/R6).
__global__ void detect_dtype(const unsigned* __restrict__ xw, int* __restrict__ flag) {
    const int t = threadIdx.x;  // 64 threads
    unsigned e = (xw[t] >> 7) & 0xFFu;
    unsigned long long m = __ballot(e >= 100u && e <= 140u);
    if (t == 0) *flag = (__popcll(m) >= 32) ? 1 : 0;
}

// edge_attr row dot We column (nontemporal: ea has zero reuse — keep L2 for x)
template <bool BF16>
__device__ __forceinline__ float edge_lin(const void* __restrict__ eav, int e,
                                          const float* __restrict__ we, float bed) {
    float acc = bed;
    if constexpr (BF16) {
        const uv4* row = (const uv4*)((const __hip_bfloat16*)eav + (size_t)e * 16);
        const uv4 p0 = __builtin_nontemporal_load(row);
        const uv4 p1 = __builtin_nontemporal_load(row + 1);
        acc = fmaf(bflo(p0[0]), we[0],  acc); acc = fmaf(bfhi(p0[0]), we[1],  acc);
        acc = fmaf(bflo(p0[1]), we[2],  acc); acc = fmaf(bfhi(p0[1]), we[3],  acc);
        acc = fmaf(bflo(p0[2]), we[4],  acc); acc = fmaf(bfhi(p0[2]), we[5],  acc);
        acc = fmaf(bflo(p0[3]), we[6],  acc); acc = fmaf(bfhi(p0[3]), we[7],  acc);
        acc = fmaf(bflo(p1[0]), we[8],  acc); acc = fmaf(bfhi(p1[0]), we[9],  acc);
        acc = fmaf(bflo(p1[1]), we[10], acc); acc = fmaf(bfhi(p1[1]), we[11], acc);
        acc = fmaf(bflo(p1[2]), we[12], acc); acc = fmaf(bfhi(p1[2]), we[13], acc);
        acc = fmaf(bflo(p1[3]), we[14], acc); acc = fmaf(bfhi(p1[3]), we[15], acc);
    } else {
        const fv4* row = (const fv4*)((const float*)eav + (size_t)e * 16);
        const fv4 q0 = __builtin_nontemporal_load(row);
        const fv4 q1 = __builtin_nontemporal_load(row + 1);
        const fv4 q2 = __builtin_nontemporal_load(row + 2);
        const fv4 q3 = __builtin_nontemporal_load(row + 3);
        acc = fmaf(q0[0], we[0],  acc); acc = fmaf(q0[1], we[1],  acc);
        acc = fmaf(q0[2], we[2],  acc); acc = fmaf(q0[3], we[3],  acc);
        acc = fmaf(q1[0], we[4],  acc); acc = fmaf(q1[1], we[5],  acc);
        acc = fmaf(q1[2], we[6],  acc); acc = fmaf(q1[3], we[7],  acc);
        acc = fmaf(q2[0], we[8],  acc); acc = fmaf(q2[1], we[9],  acc);
        acc = fmaf(q2[2], we[10], acc); acc = fmaf(q2[3], we[11], acc);
        acc = fmaf(q3[0], we[12], acc); acc = fmaf(q3[1], we[13], acc);
        acc = fmaf(q3[2], we[14], acc); acc = fmaf(q3[3], we[15], acc);
    }
    return acc;
}

// ---------------- CSR build: histogram of dst (1 edge/thread) ----------------
__global__ __launch_bounds__(256) void hist_kernel(const int* __restrict__ ei,
                                                   int* __restrict__ cnt) {
    const int oddor = ei[1] | ei[3] | ei[5] | ei[7] | ei[9] | ei[11] | ei[13] | ei[15];
    const bool idx64 = (oddor == 0);
    const long long* __restrict__ ei64 = (const long long*)ei;
    const int e = blockIdx.x * 256 + threadIdx.x;
    if (e < EE) {
        const int dst = idx64 ? (int)ei64[EE + e] : ei[EE + e];
        atomicAdd(&cnt[dst], 1);
    }
}

// ---------------- distributed scan: A) per-block scan of padded counts ----------------
__global__ __launch_bounds__(256) void scanA_kernel(const int* __restrict__ cnt,
                                                    int* __restrict__ rowptr,
                                                    int* __restrict__ part) {
    __shared__ int sdat[256];
    const int tid = threadIdx.x;
    const int ci  = blockIdx.x * 256 + tid;
    const int myc = (ci < NN) ? ((cnt[ci] + 3) & ~3) : 0;   // pad segment to x4
    sdat[tid] = myc;
    __syncthreads();
#pragma unroll
    for (int off = 1; off < 256; off <<= 1) {
        const int v = (tid >= off) ? sdat[tid - off] : 0;
        __syncthreads();
        sdat[tid] += v;
        __syncthreads();
    }
    if (ci < NN) rowptr[ci] = sdat[tid] - myc;   // block-local exclusive
    if (tid == 255) part[blockIdx.x] = sdat[255];
}

// ---------------- B) single block scans the 196 block totals ----------------
__global__ __launch_bounds__(256) void scanB_kernel(const int* __restrict__ part,
                                                    int* __restrict__ part2,
                                                    int* __restrict__ rowptr) {
    __shared__ int sdat[256];
    const int tid = threadIdx.x;
    const int v = (tid < SCAN_BLKS) ? part[tid] : 0;
    sdat[tid] = v;
    __syncthreads();
#pragma unroll
    for (int off = 1; off < 256; off <<= 1) {
        const int u = (tid >= off) ? sdat[tid - off] : 0;
        __syncthreads();
        sdat[tid] += u;
        __syncthreads();
    }
    if (tid < SCAN_BLKS) part2[tid] = sdat[tid] - v;   // exclusive base per scan-block
    if (tid == 255) rowptr[NN] = sdat[255];            // padded total
}

// ---------------- C) finalize rowptr/cursor + write pad sentinels ----------------
__global__ __launch_bounds__(256) void scanC_kernel(int* __restrict__ cursor,
                                                    int* __restrict__ rowptr,
                                                    const int* __restrict__ part2,
                                                    int* __restrict__ eid,
                                                    unsigned short* __restrict__ rsrc) {
    const int ci = blockIdx.x * 256 + threadIdx.x;
    if (ci >= NN) return;
    const int c   = cursor[ci];                 // count
    const int off = rowptr[ci] + part2[blockIdx.x];
    rowptr[ci] = off;
    cursor[ci] = off;
    const int pc = (c + 3) & ~3;
    for (int kk = c; kk < pc; kk++) {           // <=3 sentinel slots
        eid[off + kk]  = -1;
        rsrc[off + kk] = 0;
    }
}

// ---------------- CSR build: scatter (eid, src) records (1 edge/thread) ----------------
__global__ __launch_bounds__(256) void scatter_kernel(const int* __restrict__ ei,
                                                      int* __restrict__ cursor,
                                                      int* __restrict__ recs_eid,
                                                      unsigned short* __restrict__ recs_src) {
    const int oddor = ei[1] | ei[3] | ei[5] | ei[7] | ei[9] | ei[11] | ei[13] | ei[15];
    const bool idx64 = (oddor == 0);
    const long long* __restrict__ ei64 = (const long long*)ei;
    const int e = blockIdx.x * 256 + threadIdx.x;
    if (e < EE) {
        int src, dst;
        if (idx64) { src = (int)ei64[e]; dst = (int)ei64[EE + e]; }
        else       { src = ei[e];        dst = ei[EE + e]; }
        const int p = atomicAdd(&cursor[dst], 1);
        recs_eid[p]  = e;
        recs_src[p]  = (unsigned short)src;
    }
}

// ---------------- gather aggregation: one wave per node, 8-wide ILP, no atomics ----------------
template <bool BF16>
__device__ __forceinline__ float loadx(const void* __restrict__ xv, int s, int d) {
    if constexpr (BF16)
        return __bfloat162float(((const __hip_bfloat16*)xv)[(size_t)s * 64 + d]);
    else
        return ((const float*)xv)[(size_t)s * 64 + d];
}

template <bool BF16>
__device__ __forceinline__ void gather_body(
    const void* __restrict__ xv,
    const int* __restrict__ recs_eid, const unsigned short* __restrict__ recs_src,
    const int* __restrict__ rowptr,
    const void* __restrict__ eav, const void* __restrict__ Wev,
    const void* __restrict__ bev, __half* __restrict__ aggh)
{
    const int tid = threadIdx.x;
    const int d   = tid & 63;
    const int sub = tid >> 6;

    float we[16];
    float bed;
    if constexpr (BF16) {
        const __hip_bfloat16* We = (const __hip_bfloat16*)Wev;
#pragma unroll
        for (int k = 0; k < 16; k++) we[k] = __bfloat162float(We[k * 64 + d]);
        bed = __bfloat162float(((const __hip_bfloat16*)bev)[d]);
    } else {
        const float* We = (const float*)Wev;
#pragma unroll
        for (int k = 0; k < 16; k++) we[k] = We[k * 64 + d];
        bed = ((const float*)bev)[d];
    }

    const int wid = blockIdx.x * 4 + sub;
    const int nw  = gridDim.x * 4;
    for (int n = wid; n < NN; n += nw) {
        const int beg = rowptr[n];
        const int end = rowptr[n + 1];          // (end-beg) % 4 == 0 by construction
        float agg = 0.0f;
        int k = beg;
        // 8-wide: issue all 8 x-row loads before any edge_lin compute
        while (k + 8 <= end) {
            const iv4  ea4 = __builtin_nontemporal_load((const iv4*)(recs_eid + k));
            const iv4  eb4 = __builtin_nontemporal_load((const iv4*)(recs_eid + k + 4));
            const usv4 sa4 = __builtin_nontemporal_load((const usv4*)(recs_src + k));
            const usv4 sb4 = __builtin_nontemporal_load((const usv4*)(recs_src + k + 4));
            const int ee[8] = { ea4[0], ea4[1], ea4[2], ea4[3], eb4[0], eb4[1], eb4[2], eb4[3] };
            const int ss[8] = { (int)sa4[0], (int)sa4[1], (int)sa4[2], (int)sa4[3],
                                (int)sb4[0], (int)sb4[1], (int)sb4[2], (int)sb4[3] };
            float xs[8];
#pragma unroll
            for (int i = 0; i < 8; i++) xs[i] = loadx<BF16>(xv, ss[i], d);
#pragma unroll
            for (int i = 0; i < 8; i++) {
                const float a = edge_lin<BF16>(eav, max(ee[i], 0), we, bed);
                const float m = fmaxf(a + xs[i], 0.0f);
                agg += (ee[i] >= 0) ? m : 0.0f;
            }
            k += 8;
        }
        if (k < end) {   // exactly 4 remain
            const iv4  e4 = __builtin_nontemporal_load((const iv4*)(recs_eid + k));
            const usv4 s4 = __builtin_nontemporal_load((const usv4*)(recs_src + k));
            const int ee[4] = { e4[0], e4[1], e4[2], e4[3] };
            const int ss[4] = { (int)s4[0], (int)s4[1], (int)s4[2], (int)s4[3] };
            float xs[4];
#pragma unroll
            for (int i = 0; i < 4; i++) xs[i] = loadx<BF16>(xv, ss[i], d);
#pragma unroll
            for (int i = 0; i < 4; i++) {
                const float a = edge_lin<BF16>(eav, max(ee[i], 0), we, bed);
                const float m = fmaxf(a + xs[i], 0.0f);
                agg += (ee[i] >= 0) ? m : 0.0f;
            }
        }
        __builtin_nontemporal_store(__half_as_ushort(__float2half(agg)),
                                    (unsigned short*)aggh + (size_t)n * 64 + d);
    }
}

__global__ __launch_bounds__(256) void gather_agg_kernel(
    const void* x, const int* recs_eid, const unsigned short* recs_src,
    const int* rowptr, const void* ea, const void* We, const void* be,
    __half* aggh, const int* flag)
{
    if (*flag) gather_body<true >(x, recs_eid, recs_src, rowptr, ea, We, be, aggh);
    else       gather_body<false>(x, recs_eid, recs_src, rowptr, ea, We, be, aggh);
}

// ---------------- MLP (unchanged from measured-best version) ----------------
template <bool BF16>
__device__ __forceinline__ void mlp_body(
    const void* __restrict__ xv, const __half* __restrict__ aggh,
    const void* __restrict__ W1v, const void* __restrict__ b1v,
    const void* __restrict__ W2v, const void* __restrict__ b2v,
    void* __restrict__ outv, float (*sh)[64], float (*st)[64])
{
    const int tid = threadIdx.x;
    const int d   = tid & 63;
    const int w   = tid >> 6;

    float w1c[64], w2c[64], b1d, b2d;
    if constexpr (BF16) {
        const __hip_bfloat16* W1 = (const __hip_bfloat16*)W1v;
        const __hip_bfloat16* W2 = (const __hip_bfloat16*)W2v;
#pragma unroll
        for (int k = 0; k < 64; k++) {
            w1c[k] = __bfloat162float(W1[k * 64 + d]);
            w2c[k] = __bfloat162float(W2[k * 64 + d]);
        }
        b1d = __bfloat162float(((const __hip_bfloat16*)b1v)[d]);
        b2d = __bfloat162float(((const __hip_bfloat16*)b2v)[d]);
    } else {
        const float* W1 = (const float*)W1v;
        const float* W2 = (const float*)W2v;
#pragma unroll
        for (int k = 0; k < 64; k++) {
            w1c[k] = W1[k * 64 + d];
            w2c[k] = W2[k * 64 + d];
        }
        b1d = ((const float*)b1v)[d];
        b2d = ((const float*)b2v)[d];
    }

    const int stride = gridDim.x * 4;
    int node = blockIdx.x * 4 + w;

    float xs_n = 0.0f, ag_n = 0.0f;
    if (node < NN) {
        if constexpr (BF16) xs_n = __bfloat162float(((const __hip_bfloat16*)xv)[(size_t)node * 64 + d]);
        else                xs_n = ((const float*)xv)[(size_t)node * 64 + d];
        ag_n = __half2float(aggh[(size_t)node * 64 + d]);
    }

    while (node < NN) {
        const float xs_c = xs_n, ag_c = ag_n;
        const int next = node + stride;
        if (next < NN) {
            if constexpr (BF16) xs_n = __bfloat162float(((const __hip_bfloat16*)xv)[(size_t)next * 64 + d]);
            else                xs_n = ((const float*)xv)[(size_t)next * 64 + d];
            ag_n = __half2float(aggh[(size_t)next * 64 + d]);
        }

        sh[w][d] = xs_c + ag_c;

        float t = b1d;
        const float4* hv = (const float4*)sh[w];
#pragma unroll
        for (int k = 0; k < 16; k++) {
            const float4 hq = hv[k];
            t = fmaf(hq.x, w1c[4 * k],     t);
            t = fmaf(hq.y, w1c[4 * k + 1], t);
            t = fmaf(hq.z, w1c[4 * k + 2], t);
            t = fmaf(hq.w, w1c[4 * k + 3], t);
        }
        t = fmaxf(t, 0.0f);
        st[w][d] = t;

        float o = b2d;
        const float4* tv = (const float4*)st[w];
#pragma unroll
        for (int k = 0; k < 16; k++) {
            const float4 tq = tv[k];
            o = fmaf(tq.x, w2c[4 * k],     o);
            o = fmaf(tq.y, w2c[4 * k + 1], o);
            o = fmaf(tq.z, w2c[4 * k + 2], o);
            o = fmaf(tq.w, w2c[4 * k + 3], o);
        }
        if constexpr (BF16) ((__hip_bfloat16*)outv)[(size_t)node * 64 + d] = __float2bfloat16(o);
        else                ((float*)outv)[(size_t)node * 64 + d] = o;
        node = next;
    }
}

__global__ __launch_bounds__(256) void mlp_kernel(
    const void* x, const __half* aggh,
    const void* W1, const void* b1, const void* W2, const void* b2,
    void* out, const int* flag)
{
    __shared__ float sh[4][64];
    __shared__ float st[4][64];
    if (*flag) mlp_body<true >(x, aggh, W1, b1, W2, b2, out, sh, st);
    else       mlp_body<false>(x, aggh, W1, b1, W2, b2, out, sh, st);
}

extern "C" void kernel_launch(void* const* d_in, const int* in_sizes, int n_in,
                              void* d_out, int out_size, void* d_ws, size_t ws_size,
                              hipStream_t stream) {
    const void* x          = d_in[0];
    const int*  edge_index = (const int*)d_in[1];
    const void* edge_attr  = d_in[2];
    const void* We         = d_in[3];
    const void* be         = d_in[4];
    const void* W1         = d_in[5];
    const void* b1         = d_in[6];
    const void* W2         = d_in[7];
    const void* b2         = d_in[8];

    char* ws = (char*)d_ws;
    __half*         aggh   = (__half*)(ws + OFF_AGGH);
    int*            eid    = (int*)(ws + OFF_EID);
    unsigned short* rsrc   = (unsigned short*)(ws + OFF_SRC);
    int*            rowptr = (int*)(ws + OFF_ROWPTR);
    int*            cursor = (int*)(ws + OFF_CURSOR);
    int*            part   = (int*)(ws + OFF_PART);
    int*            part2  = (int*)(ws + OFF_PART2);
    int*            flag   = (int*)(ws + OFF_FLAG);

    hipMemsetAsync(cursor, 0, (size_t)NN * sizeof(int), stream);
    hipLaunchKernelGGL(detect_dtype, dim3(1), dim3(64), 0, stream,
                       (const unsigned*)x, flag);
    hipLaunchKernelGGL(hist_kernel, dim3((EE + 255) / 256), dim3(256), 0, stream,
                       edge_index, cursor);
    hipLaunchKernelGGL(scanA_kernel, dim3(SCAN_BLKS), dim3(256), 0, stream,
                       cursor, rowptr, part);
    hipLaunchKernelGGL(scanB_kernel, dim3(1), dim3(256), 0, stream,
                       part, part2, rowptr);
    hipLaunchKernelGGL(scanC_kernel, dim3(SCAN_BLKS), dim3(256), 0, stream,
                       cursor, rowptr, part2, eid, rsrc);
    hipLaunchKernelGGL(scatter_kernel, dim3((EE + 255) / 256), dim3(256), 0, stream,
                       edge_index, cursor, eid, rsrc);
    hipLaunchKernelGGL(gather_agg_kernel, dim3(2048), dim3(256), 0, stream,
                       x, eid, rsrc, rowptr, edge_attr, We, be, aggh, flag);
    hipLaunchKernelGGL(mlp_kernel, dim3(768), dim3(256), 0, stream,
                       x, aggh, W1, b1, W2, b2, d_out, flag);
}

// Round 4
// 362.902 us; speedup vs baseline: 1.2581x; 1.1069x over previous
//
#include <hip/hip_runtime.h>
#include <hip/hip_fp16.h>
#include <hip/hip_bf16.h>

#define NN 50000
#define EE 800000
#define NSEG 100000           // 2 src-halves x NN dst nodes
#define SRC_SPLIT 25000       // src < SRC_SPLIT -> half 0 (x working set 3.2MB, fits XCD L2)
#define SCAN_BLKS 391         // ceil(NSEG/256)

// ---- workspace layout (stays inside proven-safe 12.8MB + flag envelope) ----
#define OFF_AGGH   0ull          // 50000*64*2 = 6,400,000
#define OFF_EID    6400000ull    // 800000*4  = 3,200,000  -> ends  9,600,000
#define OFF_SRC    9600000ull    // 800000*2  = 1,600,000  -> ends 11,200,000
#define OFF_ROWPTR 11200000ull   // 100001*4  =   400,004  -> ends 11,600,004
#define OFF_CURSOR 11600008ull   // 100000*4  =   400,000  -> ends 12,000,008
#define OFF_PART   12000008ull   // 391*4     =     1,564  -> ends 12,001,572
#define OFF_PART2  12001576ull   // 391*4     =     1,564  -> ends 12,003,140
#define OFF_FLAG   12800000ull   // proven-safe offset from prior session

__device__ __forceinline__ float bflo(unsigned u) { return __uint_as_float(u << 16); }
__device__ __forceinline__ float bfhi(unsigned u) { return __uint_as_float(u & 0xffff0000u); }

// flag=1 if float tensors are bf16, 0 if f32 (proven R3/R6).
__global__ void detect_dtype(const unsigned* __restrict__ xw, int* __restrict__ flag) {
    const int t = threadIdx.x;  // 64 threads
    unsigned e = (xw[t] >> 7) & 0xFFu;
    unsigned long long m = __ballot(e >= 100u && e <= 140u);
    if (t == 0) *flag = (__popcll(m) >= 32) ? 1 : 0;
}

// edge_attr row (broadcast across wave) dot We column — plain cached loads (R3 lesson: no nt)
template <bool BF16>
__device__ __forceinline__ float edge_lin(const void* __restrict__ eav, int e,
                                          const float* __restrict__ we, float bed) {
    float acc = bed;
    if constexpr (BF16) {
        const uint4* row = (const uint4*)((const __hip_bfloat16*)eav + (size_t)e * 16);
        const uint4 p0 = row[0];
        const uint4 p1 = row[1];
        acc = fmaf(bflo(p0.x), we[0],  acc); acc = fmaf(bfhi(p0.x), we[1],  acc);
        acc = fmaf(bflo(p0.y), we[2],  acc); acc = fmaf(bfhi(p0.y), we[3],  acc);
        acc = fmaf(bflo(p0.z), we[4],  acc); acc = fmaf(bfhi(p0.z), we[5],  acc);
        acc = fmaf(bflo(p0.w), we[6],  acc); acc = fmaf(bfhi(p0.w), we[7],  acc);
        acc = fmaf(bflo(p1.x), we[8],  acc); acc = fmaf(bfhi(p1.x), we[9],  acc);
        acc = fmaf(bflo(p1.y), we[10], acc); acc = fmaf(bfhi(p1.y), we[11], acc);
        acc = fmaf(bflo(p1.z), we[12], acc); acc = fmaf(bfhi(p1.z), we[13], acc);
        acc = fmaf(bflo(p1.w), we[14], acc); acc = fmaf(bfhi(p1.w), we[15], acc);
    } else {
        const float4* row = (const float4*)((const float*)eav + (size_t)e * 16);
        const float4 q0 = row[0], q1 = row[1], q2 = row[2], q3 = row[3];
        acc = fmaf(q0.x, we[0],  acc); acc = fmaf(q0.y, we[1],  acc);
        acc = fmaf(q0.z, we[2],  acc); acc = fmaf(q0.w, we[3],  acc);
        acc = fmaf(q1.x, we[4],  acc); acc = fmaf(q1.y, we[5],  acc);
        acc = fmaf(q1.z, we[6],  acc); acc = fmaf(q1.w, we[7],  acc);
        acc = fmaf(q2.x, we[8],  acc); acc = fmaf(q2.y, we[9],  acc);
        acc = fmaf(q2.z, we[10], acc); acc = fmaf(q2.w, we[11], acc);
        acc = fmaf(q3.x, we[12], acc); acc = fmaf(q3.y, we[13], acc);
        acc = fmaf(q3.z, we[14], acc); acc = fmaf(q3.w, we[15], acc);
    }
    return acc;
}

// ---------------- CSR build: histogram over (src-half, dst) ----------------
__global__ __launch_bounds__(256) void hist_kernel(const int* __restrict__ ei,
                                                   int* __restrict__ cnt) {
    const int oddor = ei[1] | ei[3] | ei[5] | ei[7] | ei[9] | ei[11] | ei[13] | ei[15];
    const bool idx64 = (oddor == 0);
    const long long* __restrict__ ei64 = (const long long*)ei;
    const int e = blockIdx.x * 256 + threadIdx.x;
    if (e < EE) {
        int src, dst;
        if (idx64) { src = (int)ei64[e]; dst = (int)ei64[EE + e]; }
        else       { src = ei[e];        dst = ei[EE + e]; }
        const int h = (src >= SRC_SPLIT) ? 1 : 0;
        atomicAdd(&cnt[h * NN + dst], 1);
    }
}

// ---------------- distributed scan A: per-block scan of NSEG counts ----------------
__global__ __launch_bounds__(256) void scanA_kernel(const int* __restrict__ cnt,
                                                    int* __restrict__ rowptr,
                                                    int* __restrict__ part) {
    __shared__ int sdat[256];
    const int tid = threadIdx.x;
    const int ci  = blockIdx.x * 256 + tid;
    const int myc = (ci < NSEG) ? cnt[ci] : 0;
    sdat[tid] = myc;
    __syncthreads();
#pragma unroll
    for (int off = 1; off < 256; off <<= 1) {
        const int v = (tid >= off) ? sdat[tid - off] : 0;
        __syncthreads();
        sdat[tid] += v;
        __syncthreads();
    }
    if (ci < NSEG) rowptr[ci] = sdat[tid] - myc;   // block-local exclusive
    if (tid == 255) part[blockIdx.x] = sdat[255];
}

// ---------------- scan B: one block scans the SCAN_BLKS totals ----------------
__global__ __launch_bounds__(512) void scanB_kernel(const int* __restrict__ part,
                                                    int* __restrict__ part2,
                                                    int* __restrict__ rowptr) {
    __shared__ int sdat[512];
    const int tid = threadIdx.x;
    const int v = (tid < SCAN_BLKS) ? part[tid] : 0;
    sdat[tid] = v;
    __syncthreads();
#pragma unroll
    for (int off = 1; off < 512; off <<= 1) {
        const int u = (tid >= off) ? sdat[tid - off] : 0;
        __syncthreads();
        sdat[tid] += u;
        __syncthreads();
    }
    if (tid < SCAN_BLKS) part2[tid] = sdat[tid] - v;   // exclusive base per scan-block
    if (tid == 511) rowptr[NSEG] = sdat[511];          // total == EE
}

// ---------------- scan C: finalize rowptr + cursor init ----------------
__global__ __launch_bounds__(256) void scanC_kernel(int* __restrict__ cursor,
                                                    int* __restrict__ rowptr,
                                                    const int* __restrict__ part2) {
    const int ci = blockIdx.x * 256 + threadIdx.x;
    if (ci >= NSEG) return;
    const int off = rowptr[ci] + part2[blockIdx.x];
    rowptr[ci] = off;
    cursor[ci] = off;
}

// ---------------- scatter (eid, src) into (half, dst) segments ----------------
__global__ __launch_bounds__(256) void scatter_kernel(const int* __restrict__ ei,
                                                      int* __restrict__ cursor,
                                                      int* __restrict__ recs_eid,
                                                      unsigned short* __restrict__ recs_src) {
    const int oddor = ei[1] | ei[3] | ei[5] | ei[7] | ei[9] | ei[11] | ei[13] | ei[15];
    const bool idx64 = (oddor == 0);
    const long long* __restrict__ ei64 = (const long long*)ei;
    const int e = blockIdx.x * 256 + threadIdx.x;
    if (e < EE) {
        int src, dst;
        if (idx64) { src = (int)ei64[e]; dst = (int)ei64[EE + e]; }
        else       { src = ei[e];        dst = ei[EE + e]; }
        const int h = (src >= SRC_SPLIT) ? 1 : 0;
        const int p = atomicAdd(&cursor[h * NN + dst], 1);
        recs_eid[p] = e;
        recs_src[p] = (unsigned short)src;
    }
}

// ---------------- gather: two src-half sweeps, one wave per node, no atomics ----------------
template <bool BF16>
__device__ __forceinline__ float loadx(const void* __restrict__ xv, int s, int d) {
    if constexpr (BF16)
        return __bfloat162float(((const __hip_bfloat16*)xv)[(size_t)s * 64 + d]);
    else
        return ((const float*)xv)[(size_t)s * 64 + d];
}

template <bool BF16>
__device__ __forceinline__ float seg_accum(
    const void* __restrict__ xv,
    const int* __restrict__ recs_eid, const unsigned short* __restrict__ recs_src,
    const void* __restrict__ eav, const float* __restrict__ we, float bed,
    int beg, int end, int d, float agg)
{
    int k = beg;
    for (; k + 4 <= end; k += 4) {
        const int e0 = recs_eid[k],     e1 = recs_eid[k + 1];
        const int e2 = recs_eid[k + 2], e3 = recs_eid[k + 3];
        const int s0 = (int)recs_src[k],     s1 = (int)recs_src[k + 1];
        const int s2 = (int)recs_src[k + 2], s3 = (int)recs_src[k + 3];
        const float x0 = loadx<BF16>(xv, s0, d);
        const float x1 = loadx<BF16>(xv, s1, d);
        const float x2 = loadx<BF16>(xv, s2, d);
        const float x3 = loadx<BF16>(xv, s3, d);
        const float a0 = edge_lin<BF16>(eav, e0, we, bed);
        const float a1 = edge_lin<BF16>(eav, e1, we, bed);
        const float a2 = edge_lin<BF16>(eav, e2, we, bed);
        const float a3 = edge_lin<BF16>(eav, e3, we, bed);
        agg += fmaxf(a0 + x0, 0.0f);
        agg += fmaxf(a1 + x1, 0.0f);
        agg += fmaxf(a2 + x2, 0.0f);
        agg += fmaxf(a3 + x3, 0.0f);
    }
    for (; k < end; ++k) {
        const int e0 = recs_eid[k];
        const int s0 = (int)recs_src[k];
        const float x0 = loadx<BF16>(xv, s0, d);
        agg += fmaxf(edge_lin<BF16>(eav, e0, we, bed) + x0, 0.0f);
    }
    return agg;
}

template <bool BF16>
__device__ __forceinline__ void gather_body(
    const void* __restrict__ xv,
    const int* __restrict__ recs_eid, const unsigned short* __restrict__ recs_src,
    const int* __restrict__ rowptr,
    const void* __restrict__ eav, const void* __restrict__ Wev,
    const void* __restrict__ bev, __half* __restrict__ aggh)
{
    const int tid = threadIdx.x;
    const int d   = tid & 63;
    const int sub = tid >> 6;

    float we[16];
    float bed;
    if constexpr (BF16) {
        const __hip_bfloat16* We = (const __hip_bfloat16*)Wev;
#pragma unroll
        for (int k = 0; k < 16; k++) we[k] = __bfloat162float(We[k * 64 + d]);
        bed = __bfloat162float(((const __hip_bfloat16*)bev)[d]);
    } else {
        const float* We = (const float*)Wev;
#pragma unroll
        for (int k = 0; k < 16; k++) we[k] = We[k * 64 + d];
        bed = ((const float*)bev)[d];
    }

    const int wid = blockIdx.x * 4 + sub;
    const int nw  = gridDim.x * 4;

    // sweep 0: src-half 0 (x rows 0..SRC_SPLIT-1 -> 3.2MB, L2-resident)
    for (int n = wid; n < NN; n += nw) {
        const int beg = rowptr[n];
        const int end = rowptr[n + 1];
        const float agg = seg_accum<BF16>(xv, recs_eid, recs_src, eav, we, bed,
                                          beg, end, d, 0.0f);
        aggh[(size_t)n * 64 + d] = __float2half(agg);
    }
    // sweep 1: src-half 1 (x rows SRC_SPLIT..NN-1), accumulate onto sweep-0 partials
    for (int n = wid; n < NN; n += nw) {
        const int beg = rowptr[NN + n];
        const int end = rowptr[NN + n + 1];
        if (beg == end) continue;
        const float prev = __half2float(aggh[(size_t)n * 64 + d]);
        const float agg = seg_accum<BF16>(xv, recs_eid, recs_src, eav, we, bed,
                                          beg, end, d, prev);
        aggh[(size_t)n * 64 + d] = __float2half(agg);
    }
}

__global__ __launch_bounds__(256) void gather_agg_kernel(
    const void* x, const int* recs_eid, const unsigned short* recs_src,
    const int* rowptr, const void* ea, const void* We, const void* be,
    __half* aggh, const int* flag)
{
    if (*flag) gather_body<true >(x, recs_eid, recs_src, rowptr, ea, We, be, aggh);
    else       gather_body<false>(x, recs_eid, recs_src, rowptr, ea, We, be, aggh);
}

// ---------------- MLP (unchanged from measured-best version) ----------------
template <bool BF16>
__device__ __forceinline__ void mlp_body(
    const void* __restrict__ xv, const __half* __restrict__ aggh,
    const void* __restrict__ W1v, const void* __restrict__ b1v,
    const void* __restrict__ W2v, const void* __restrict__ b2v,
    void* __restrict__ outv, float (*sh)[64], float (*st)[64])
{
    const int tid = threadIdx.x;
    const int d   = tid & 63;
    const int w   = tid >> 6;

    float w1c[64], w2c[64], b1d, b2d;
    if constexpr (BF16) {
        const __hip_bfloat16* W1 = (const __hip_bfloat16*)W1v;
        const __hip_bfloat16* W2 = (const __hip_bfloat16*)W2v;
#pragma unroll
        for (int k = 0; k < 64; k++) {
            w1c[k] = __bfloat162float(W1[k * 64 + d]);
            w2c[k] = __bfloat162float(W2[k * 64 + d]);
        }
        b1d = __bfloat162float(((const __hip_bfloat16*)b1v)[d]);
        b2d = __bfloat162float(((const __hip_bfloat16*)b2v)[d]);
    } else {
        const float* W1 = (const float*)W1v;
        const float* W2 = (const float*)W2v;
#pragma unroll
        for (int k = 0; k < 64; k++) {
            w1c[k] = W1[k * 64 + d];
            w2c[k] = W2[k * 64 + d];
        }
        b1d = ((const float*)b1v)[d];
        b2d = ((const float*)b2v)[d];
    }

    const int stride = gridDim.x * 4;
    int node = blockIdx.x * 4 + w;

    float xs_n = 0.0f, ag_n = 0.0f;
    if (node < NN) {
        if constexpr (BF16) xs_n = __bfloat162float(((const __hip_bfloat16*)xv)[(size_t)node * 64 + d]);
        else                xs_n = ((const float*)xv)[(size_t)node * 64 + d];
        ag_n = __half2float(aggh[(size_t)node * 64 + d]);
    }

    while (node < NN) {
        const float xs_c = xs_n, ag_c = ag_n;
        const int next = node + stride;
        if (next < NN) {
            if constexpr (BF16) xs_n = __bfloat162float(((const __hip_bfloat16*)xv)[(size_t)next * 64 + d]);
            else                xs_n = ((const float*)xv)[(size_t)next * 64 + d];
            ag_n = __half2float(aggh[(size_t)next * 64 + d]);
        }

        sh[w][d] = xs_c + ag_c;

        float t = b1d;
        const float4* hv = (const float4*)sh[w];
#pragma unroll
        for (int k = 0; k < 16; k++) {
            const float4 hq = hv[k];
            t = fmaf(hq.x, w1c[4 * k],     t);
            t = fmaf(hq.y, w1c[4 * k + 1], t);
            t = fmaf(hq.z, w1c[4 * k + 2], t);
            t = fmaf(hq.w, w1c[4 * k + 3], t);
        }
        t = fmaxf(t, 0.0f);
        st[w][d] = t;

        float o = b2d;
        const float4* tv = (const float4*)st[w];
#pragma unroll
        for (int k = 0; k < 16; k++) {
            const float4 tq = tv[k];
            o = fmaf(tq.x, w2c[4 * k],     o);
            o = fmaf(tq.y, w2c[4 * k + 1], o);
            o = fmaf(tq.z, w2c[4 * k + 2], o);
            o = fmaf(tq.w, w2c[4 * k + 3], o);
        }
        if constexpr (BF16) ((__hip_bfloat16*)outv)[(size_t)node * 64 + d] = __float2bfloat16(o);
        else                ((float*)outv)[(size_t)node * 64 + d] = o;
        node = next;
    }
}

__global__ __launch_bounds__(256) void mlp_kernel(
    const void* x, const __half* aggh,
    const void* W1, const void* b1, const void* W2, const void* b2,
    void* out, const int* flag)
{
    __shared__ float sh[4][64];
    __shared__ float st[4][64];
    if (*flag) mlp_body<true >(x, aggh, W1, b1, W2, b2, out, sh, st);
    else       mlp_body<false>(x, aggh, W1, b1, W2, b2, out, sh, st);
}

extern "C" void kernel_launch(void* const* d_in, const int* in_sizes, int n_in,
                              void* d_out, int out_size, void* d_ws, size_t ws_size,
                              hipStream_t stream) {
    const void* x          = d_in[0];
    const int*  edge_index = (const int*)d_in[1];
    const void* edge_attr  = d_in[2];
    const void* We         = d_in[3];
    const void* be         = d_in[4];
    const void* W1         = d_in[5];
    const void* b1         = d_in[6];
    const void* W2         = d_in[7];
    const void* b2         = d_in[8];

    char* ws = (char*)d_ws;
    __half*         aggh   = (__half*)(ws + OFF_AGGH);
    int*            eid    = (int*)(ws + OFF_EID);
    unsigned short* rsrc   = (unsigned short*)(ws + OFF_SRC);
    int*            rowptr = (int*)(ws + OFF_ROWPTR);
    int*            cursor = (int*)(ws + OFF_CURSOR);
    int*            part   = (int*)(ws + OFF_PART);
    int*            part2  = (int*)(ws + OFF_PART2);
    int*            flag   = (int*)(ws + OFF_FLAG);

    hipMemsetAsync(cursor, 0, (size_t)NSEG * sizeof(int), stream);
    hipLaunchKernelGGL(detect_dtype, dim3(1), dim3(64), 0, stream,
                       (const unsigned*)x, flag);
    hipLaunchKernelGGL(hist_kernel, dim3((EE + 255) / 256), dim3(256), 0, stream,
                       edge_index, cursor);
    hipLaunchKernelGGL(scanA_kernel, dim3(SCAN_BLKS), dim3(256), 0, stream,
                       cursor, rowptr, part);
    hipLaunchKernelGGL(scanB_kernel, dim3(1), dim3(512), 0, stream,
                       part, part2, rowptr);
    hipLaunchKernelGGL(scanC_kernel, dim3(SCAN_BLKS), dim3(256), 0, stream,
                       cursor, rowptr, part2);
    hipLaunchKernelGGL(scatter_kernel, dim3((EE + 255) / 256), dim3(256), 0, stream,
                       edge_index, cursor, eid, rsrc);
    hipLaunchKernelGGL(gather_agg_kernel, dim3(2048), dim3(256), 0, stream,
                       x, eid, rsrc, rowptr, edge_attr, We, be, aggh, flag);
    hipLaunchKernelGGL(mlp_kernel, dim3(768), dim3(256), 0, stream,
                       x, aggh, W1, b1, W2, b2, d_out, flag);
}